// Round 2
// baseline (1756.197 us; speedup 1.0000x reference)
//
#include <hip/hip_runtime.h>
#include <hip/hip_bf16.h>
#include <math.h>

#define B_   2048
#define N_   38
#define E_   4
#define DIN_ 9
#define H0_  256
#define H1_  256
#define L0_  512
#define M_   (B_ * N_)

// ---------- storage-type helpers (fp32 or bf16 activations) ----------
struct __align__(8) bf4 { __hip_bfloat16 x, y, z, w; };

__device__ __forceinline__ float4 ld4v(const float* p) { return *(const float4*)p; }
__device__ __forceinline__ float4 ld4v(const __hip_bfloat16* p) {
  bf4 v = *(const bf4*)p;
  return make_float4(__bfloat162float(v.x), __bfloat162float(v.y),
                     __bfloat162float(v.z), __bfloat162float(v.w));
}
__device__ __forceinline__ void st4v(float* p, float4 v) { *(float4*)p = v; }
__device__ __forceinline__ void st4v(__hip_bfloat16* p, float4 v) {
  bf4 o;
  o.x = __float2bfloat16(v.x); o.y = __float2bfloat16(v.y);
  o.z = __float2bfloat16(v.z); o.w = __float2bfloat16(v.w);
  *(bf4*)p = o;
}
__device__ __forceinline__ float ld1v(const float* p) { return *p; }
__device__ __forceinline__ float ld1v(const __hip_bfloat16* p) { return __bfloat162float(*p); }

static __device__ __forceinline__ float selc(const float4 v, int j) {
  return (j == 0) ? v.x : ((j == 1) ? v.y : ((j == 2) ? v.z : v.w));
}

// 4c x 12m register-tile FMA block
__device__ __forceinline__ void fma_tile12(const float* __restrict__ zr, float4 w,
                                           float (&acc)[4][12]) {
#pragma unroll
  for (int l4 = 0; l4 < 3; ++l4) {
    float4 zv = *(const float4*)&zr[l4 * 4];
#pragma unroll
    for (int j = 0; j < 4; ++j) {
      float wj = selc(w, j);
      acc[j][l4 * 4 + 0] = fmaf(zv.x, wj, acc[j][l4 * 4 + 0]);
      acc[j][l4 * 4 + 1] = fmaf(zv.y, wj, acc[j][l4 * 4 + 1]);
      acc[j][l4 * 4 + 2] = fmaf(zv.z, wj, acc[j][l4 * 4 + 2]);
      acc[j][l4 * 4 + 3] = fmaf(zv.w, wj, acc[j][l4 * 4 + 3]);
    }
  }
}

__global__ void k_zero(float* __restrict__ p) { p[threadIdx.x] = 0.f; }

// WcatT0: [45][256]  r<9 -> cWs0[c][r]; else rr=r-9, e=rr/9, f=rr%9 -> cWe0[c*4+e][f]
__global__ void k_build_w0(const float* __restrict__ Ws, const float* __restrict__ We,
                           float* __restrict__ WT) {
  int i = blockIdx.x * 256 + threadIdx.x;
  if (i >= 45 * 256) return;
  int r = i / 256, c = i % 256;
  float v;
  if (r < 9) v = Ws[c * 9 + r];
  else { int rr = r - 9; int e = rr / 9, f = rr % 9; v = We[(c * 4 + e) * 9 + f]; }
  WT[i] = v;
}

// WcatT1: [1280][256]  r<256 -> cWs1[c][r]; else rr=r-256, e=rr>>8, f=rr&255 -> cWe1[c*4+e][f]
__global__ void k_build_w1(const float* __restrict__ Ws, const float* __restrict__ We,
                           float* __restrict__ WT) {
  int i = blockIdx.x * 256 + threadIdx.x;
  if (i >= 1280 * 256) return;
  int r = i / 256, c = i % 256;
  float v;
  if (r < 256) v = Ws[c * 256 + r];
  else { int rr = r - 256; int e = rr >> 8, f = rr & 255; v = We[(c * 4 + e) * 256 + f]; }
  WT[i] = v;
}

// lW0T: [256][512]
__global__ void k_build_w2(const float* __restrict__ W, float* __restrict__ WT) {
  int i = blockIdx.x * 256 + threadIdx.x;
  if (i >= 256 * 512) return;
  int f = i / 512, c = i % 512;
  WT[i] = W[c * 256 + f];
}

// fWT: [512][18]
__global__ void k_build_w3(const float* __restrict__ W, float* __restrict__ WT) {
  int i = blockIdx.x * 256 + threadIdx.x;
  if (i >= 512 * 18) return;
  int k = i / 18, c = i % 18;
  WT[i] = W[c * 512 + k];
}

// ---------------- gconv layer 0 (K=45) ----------------
template <typename ST>
__global__ __launch_bounds__(256) void k_gconv0(
    const float* __restrict__ adj, const float* __restrict__ x,
    const float* __restrict__ WT, const float* __restrict__ bs,
    const float* __restrict__ be, ST* __restrict__ g) {
  __shared__ __align__(16) float adjF[E_ * N_ * N_];
  __shared__ __align__(16) float xc[45 * 48];
  __shared__ __align__(16) float arow[E_ * 48];
  const int b = blockIdx.x, tid = threadIdx.x;
  const size_t abase = (size_t)b * (E_ * N_ * N_);
  for (int i = tid; i < E_ * N_ * N_; i += 256) adjF[i] = adj[abase + i];
  for (int i = tid; i < N_ * DIN_; i += 256) {
    int n = i / DIN_;
    float v = x[(size_t)b * (N_ * DIN_) + i];
    xc[(i % DIN_) * 48 + n] = (n & 1) ? v : 0.f;   // MASK zeroes even rows
  }
  __syncthreads();
  for (int i = tid; i < E_ * N_; i += 256) {
    int e = i / N_, m = i % N_;
    const float* ar = &adjF[(e * N_ + m) * N_];
    float s = 0.f;
    for (int n = 0; n < N_; ++n) s += ar[n];
    arow[e * 48 + m] = s;
  }
  for (int i = tid; i < 36 * N_; i += 256) {
    int m = i % N_, ef = i / N_;
    int e = ef / 9, f = ef % 9;
    const float* ar = &adjF[(e * N_ + m) * N_];
    float s = 0.f;
    for (int n = 0; n < N_; ++n) s += ar[n] * xc[f * 48 + n];
    xc[(9 + ef) * 48 + m] = s;
  }
  __syncthreads();
  const int cg = tid & 63, mg = tid >> 6;
  const int c0 = cg * 4, mb = mg * 12;
  float acc[4][12];
#pragma unroll
  for (int j = 0; j < 4; ++j) {
    float bsv = bs[c0 + j];
    float b0 = be[(c0 + j) * 4 + 0], b1 = be[(c0 + j) * 4 + 1];
    float b2 = be[(c0 + j) * 4 + 2], b3 = be[(c0 + j) * 4 + 3];
#pragma unroll
    for (int l = 0; l < 12; ++l) {
      int m = mb + l;
      acc[j][l] = bsv + arow[0 * 48 + m] * b0 + arow[1 * 48 + m] * b1 +
                  arow[2 * 48 + m] * b2 + arow[3 * 48 + m] * b3;
    }
  }
  for (int k = 0; k < 45; ++k) {
    float4 w = *(const float4*)&WT[k * 256 + c0];
    fma_tile12(&xc[k * 48 + mb], w, acc);
  }
#pragma unroll
  for (int l = 0; l < 12; ++l) {
    int m = mb + l;
    if (m < N_) {
      float4 o; o.x = acc[0][l]; o.y = acc[1][l]; o.z = acc[2][l]; o.w = acc[3][l];
      st4v(&g[((size_t)b * N_ + m) * H0_ + c0], o);
    }
  }
}

// ---------------- gconv layer 1 (K=1280), BN0+ReLU fused on load ----------------
template <typename ST>
__global__ __launch_bounds__(256) void k_gconv1(
    const float* __restrict__ adj, const ST* __restrict__ g0,
    const float* __restrict__ WT, const float* __restrict__ bs,
    const float* __restrict__ be, const float* __restrict__ st,
    const float* __restrict__ gam, const float* __restrict__ bet,
    ST* __restrict__ g1) {
  __shared__ __align__(16) float adjT[N_ * N_ * E_];  // [m][n][e]
  __shared__ __align__(16) float h1N[N_ * 36];        // [n][fl+pad]
  __shared__ __align__(16) float h1T[32 * 48];        // [fl][m+pad]
  __shared__ __align__(16) float zT[128 * 48];        // [e*32+fl][m+pad]
  __shared__ __align__(16) float arow[E_ * 48];
  __shared__ float aS[N_], bS[N_];
  const int b = blockIdx.x, tid = threadIdx.x;
  if (tid < N_) {
    const float cnt = 2048.f * 256.f;
    float mu = st[tid * 2] / cnt;
    float var = st[tid * 2 + 1] / cnt - mu * mu;
    float a = rsqrtf(var + 1e-5f) * gam[tid];
    aS[tid] = a;
    bS[tid] = bet[tid] - mu * a;
  }
  const size_t abase = (size_t)b * (E_ * N_ * N_);
  for (int i = tid; i < E_ * N_ * N_; i += 256) {
    int e = i / (N_ * N_), r = i % (N_ * N_);
    adjT[r * E_ + e] = adj[abase + i];
  }
  __syncthreads();
  for (int i = tid; i < E_ * N_; i += 256) {
    int e = i / N_, m = i % N_;
    float s = 0.f;
    for (int n = 0; n < N_; ++n) s += adjT[(m * N_ + n) * E_ + e];
    arow[e * 48 + m] = s;
  }
  __syncthreads();
  const int cg = tid & 63, mg = tid >> 6;
  const int c0 = cg * 4, mb = mg * 12;
  float acc[4][12];
#pragma unroll
  for (int j = 0; j < 4; ++j) {
    float bsv = bs[c0 + j];
    float b0 = be[(c0 + j) * 4 + 0], b1 = be[(c0 + j) * 4 + 1];
    float b2 = be[(c0 + j) * 4 + 2], b3 = be[(c0 + j) * 4 + 3];
#pragma unroll
    for (int l = 0; l < 12; ++l) {
      int m = mb + l;
      acc[j][l] = bsv + arow[0 * 48 + m] * b0 + arow[1 * 48 + m] * b1 +
                  arow[2 * 48 + m] * b2 + arow[3 * 48 + m] * b3;
    }
  }
  for (int fc = 0; fc < 8; ++fc) {
    const int f0 = fc * 32;
    __syncthreads();
    for (int i = tid; i < N_ * 32; i += 256) {
      int n = i >> 5, fl = i & 31;
      float raw = ld1v(&g0[((size_t)b * N_ + n) * H0_ + f0 + fl]);
      float v = fmaxf(fmaf(raw, aS[n], bS[n]), 0.f);
      h1N[n * 36 + fl] = v;
      h1T[fl * 48 + n] = v;
    }
    __syncthreads();
    if (tid < 152) {  // z chunk: (m, f-oct) -> z[m][e=0..3][8 f]
      int m = tid % N_, fo = tid / N_;
      float az[4][8];
#pragma unroll
      for (int e = 0; e < 4; ++e)
#pragma unroll
        for (int f = 0; f < 8; ++f) az[e][f] = 0.f;
      for (int n = 0; n < N_; ++n) {
        float4 av = *(const float4*)&adjT[(m * N_ + n) * E_];
        float4 ha = *(const float4*)&h1N[n * 36 + fo * 8];
        float4 hb = *(const float4*)&h1N[n * 36 + fo * 8 + 4];
#pragma unroll
        for (int e = 0; e < 4; ++e) {
          float ae = selc(av, e);
          az[e][0] = fmaf(ae, ha.x, az[e][0]);
          az[e][1] = fmaf(ae, ha.y, az[e][1]);
          az[e][2] = fmaf(ae, ha.z, az[e][2]);
          az[e][3] = fmaf(ae, ha.w, az[e][3]);
          az[e][4] = fmaf(ae, hb.x, az[e][4]);
          az[e][5] = fmaf(ae, hb.y, az[e][5]);
          az[e][6] = fmaf(ae, hb.z, az[e][6]);
          az[e][7] = fmaf(ae, hb.w, az[e][7]);
        }
      }
#pragma unroll
      for (int e = 0; e < 4; ++e)
#pragma unroll
        for (int f = 0; f < 8; ++f)
          zT[(e * 32 + fo * 8 + f) * 48 + m] = az[e][f];
    }
    __syncthreads();
    for (int fl = 0; fl < 32; ++fl) {
      float4 w = *(const float4*)&WT[(f0 + fl) * 256 + c0];
      fma_tile12(&h1T[fl * 48 + mb], w, acc);
    }
    for (int ef = 0; ef < 128; ++ef) {
      int e = ef >> 5, fl = ef & 31;
      float4 w = *(const float4*)&WT[(256 + e * 256 + f0 + fl) * 256 + c0];
      fma_tile12(&zT[ef * 48 + mb], w, acc);
    }
  }
#pragma unroll
  for (int l = 0; l < 12; ++l) {
    int m = mb + l;
    if (m < N_) {
      float4 o; o.x = acc[0][l]; o.y = acc[1][l]; o.z = acc[2][l]; o.w = acc[3][l];
      st4v(&g1[((size_t)b * N_ + m) * H1_ + c0], o);
    }
  }
}

// ---------------- linear 256 -> 512, BN1+ReLU fused on load ----------------
template <typename ST>
__global__ __launch_bounds__(256) void k_lin0(
    const ST* __restrict__ g1, const float* __restrict__ WT,
    const float* __restrict__ bias, const float* __restrict__ st,
    const float* __restrict__ gam, const float* __restrict__ bet,
    ST* __restrict__ g2) {
  __shared__ __align__(16) float hT[256 * 40];
  __shared__ float aS[N_], bS[N_];
  const int b = blockIdx.x, tid = threadIdx.x;
  if (tid < N_) {
    const float cnt = 2048.f * 256.f;
    float mu = st[tid * 2] / cnt;
    float var = st[tid * 2 + 1] / cnt - mu * mu;
    float a = rsqrtf(var + 1e-5f) * gam[tid];
    aS[tid] = a;
    bS[tid] = bet[tid] - mu * a;
  }
  __syncthreads();
  for (int i = tid; i < N_ * H1_; i += 256) {
    int m = i >> 8, f = i & 255;
    float raw = ld1v(&g1[((size_t)b * N_ + m) * H1_ + f]);
    hT[f * 40 + m] = fmaxf(fmaf(raw, aS[m], bS[m]), 0.f);
  }
  __syncthreads();
  const int cg = tid & 127, mg = tid >> 7;
  const int c0 = cg * 4, mb = mg * 20;
  float acc[4][20];
#pragma unroll
  for (int j = 0; j < 4; ++j) {
    float bv = bias[c0 + j];
#pragma unroll
    for (int l = 0; l < 20; ++l) acc[j][l] = bv;
  }
  for (int k = 0; k < H1_; ++k) {
    float4 w = *(const float4*)&WT[k * L0_ + c0];
    const float* zr = &hT[k * 40 + mb];
#pragma unroll
    for (int l4 = 0; l4 < 5; ++l4) {
      float4 zv = *(const float4*)&zr[l4 * 4];
#pragma unroll
      for (int j = 0; j < 4; ++j) {
        float wj = selc(w, j);
        acc[j][l4 * 4 + 0] = fmaf(zv.x, wj, acc[j][l4 * 4 + 0]);
        acc[j][l4 * 4 + 1] = fmaf(zv.y, wj, acc[j][l4 * 4 + 1]);
        acc[j][l4 * 4 + 2] = fmaf(zv.z, wj, acc[j][l4 * 4 + 2]);
        acc[j][l4 * 4 + 3] = fmaf(zv.w, wj, acc[j][l4 * 4 + 3]);
      }
    }
  }
#pragma unroll
  for (int l = 0; l < 20; ++l) {
    int m = mb + l;
    if (m < N_) {
      float4 o; o.x = acc[0][l]; o.y = acc[1][l]; o.z = acc[2][l]; o.w = acc[3][l];
      st4v(&g2[((size_t)b * N_ + m) * L0_ + c0], o);
    }
  }
}

// ---------------- BN stats: per-n sum/sumsq over (B x C); grid (38, 32) ----------------
template <typename ST>
__global__ __launch_bounds__(256) void k_stats(const ST* __restrict__ g, int C,
                                               float* __restrict__ st) {
  int n = blockIdx.x, s = blockIdx.y, tid = threadIdx.x;
  int C4 = C >> 2;
  float sum = 0.f, sq = 0.f;
  int per = 64 * C4;
  for (int j = tid; j < per; j += 256) {
    int bb = (s << 6) + j / C4, cc = j % C4;
    float4 v = ld4v(&g[((size_t)(bb * N_ + n) * C4 + cc) * 4]);
    sum += v.x + v.y + v.z + v.w;
    sq += v.x * v.x + v.y * v.y + v.z * v.z + v.w * v.w;
  }
  for (int off = 32; off; off >>= 1) {
    sum += __shfl_down(sum, off);
    sq += __shfl_down(sq, off);
  }
  __shared__ float rs[4], rq[4];
  int w = tid >> 6, l = tid & 63;
  if (!l) { rs[w] = sum; rq[w] = sq; }
  __syncthreads();
  if (!tid) {
    float S = 0.f, Q = 0.f;
    for (int i = 0; i < 4; ++i) { S += rs[i]; Q += rq[i]; }
    atomicAdd(&st[n * 2], S);
    atomicAdd(&st[n * 2 + 1], Q);
  }
}

// ---------------- final linear 512->18 + coupling + logdet, BN2+ReLU fused ----------------
template <typename ST>
__global__ __launch_bounds__(384) void k_final(
    const ST* __restrict__ g2, const float* __restrict__ x,
    const float* __restrict__ fWT, const float* __restrict__ fb,
    const float* __restrict__ st, const float* __restrict__ gam,
    const float* __restrict__ bet, float* __restrict__ out) {
  __shared__ __align__(16) float h3T[128 * 40];
  __shared__ float logits[N_ * 18];
  __shared__ float red[512];
  __shared__ float aS[N_], bS[N_];
  const int b = blockIdx.x, tid = threadIdx.x;
  if (tid < N_) {
    const float cnt = 2048.f * 512.f;
    float mu = st[tid * 2] / cnt;
    float var = st[tid * 2 + 1] / cnt - mu * mu;
    float a = rsqrtf(var + 1e-5f) * gam[tid];
    aS[tid] = a;
    bS[tid] = bet[tid] - mu * a;
  }
  __syncthreads();
  const bool act = tid < 342;
  const int m = tid / 9, cp = tid % 9, c0 = cp * 2;
  float acc0 = 0.f, acc1 = 0.f;
  if (act) { acc0 = fb[c0]; acc1 = fb[c0 + 1]; }
  for (int kc = 0; kc < 4; ++kc) {
    __syncthreads();
    for (int i = tid; i < N_ * 128; i += 384) {
      int mm = i >> 7, kl = i & 127;
      float raw = ld1v(&g2[((size_t)b * N_ + mm) * L0_ + (kc << 7) + kl]);
      h3T[kl * 40 + mm] = fmaxf(fmaf(raw, aS[mm], bS[mm]), 0.f);
    }
    __syncthreads();
    if (act) {
      for (int kl = 0; kl < 128; ++kl) {
        float v = h3T[kl * 40 + m];
        float2 w = *(const float2*)&fWT[((kc << 7) + kl) * 18 + c0];
        acc0 = fmaf(v, w.x, acc0);
        acc1 = fmaf(v, w.y, acc1);
      }
    }
  }
  __syncthreads();
  if (act) { logits[m * 18 + c0] = acc0; logits[m * 18 + c0 + 1] = acc1; }
  __syncthreads();
  float ls = 0.f;
  if (tid < 342) {
    int mm = tid / 9, d = tid % 9;
    float sl = logits[mm * 18 + d];
    float tv = logits[mm * 18 + 9 + d];
    float xv = x[((size_t)b * N_ + mm) * 9 + d];
    float sg = 1.f / (1.f + expf(-sl));
    float o = (mm & 1) ? xv : (xv + tv) * sg;
    out[((size_t)b * N_ + mm) * 9 + d] = o;
    ls = (sl >= 0.f) ? -log1pf(expf(-sl)) : (sl - log1pf(expf(sl)));
  }
  red[tid] = ls;
  for (int i = tid + 384; i < 512; i += 384) red[i] = 0.f;
  __syncthreads();
  for (int s = 256; s >= 1; s >>= 1) {
    if (tid < s) red[tid] += red[tid + s];
    __syncthreads();
  }
  if (!tid) out[(size_t)B_ * 342 + b] = red[0];
}

// ---------------- host side ----------------
template <typename ST>
static void run_pipeline(const float* adj, const float* x,
                         const float* cbs0, const float* cbe0, const float* cg0, const float* cb0,
                         const float* cbs1, const float* cbe1, const float* cg1, const float* cb1,
                         const float* lb0, const float* lg0, const float* lbb0,
                         const float* fb,
                         float* stats, float* wt0, float* wt1, float* wt2, float* wt3,
                         ST* bufA, ST* bufB, float* out, hipStream_t stream) {
  ST* g0 = bufA;            // M x 256
  ST* g1 = bufB;            // M x 256
  ST* g2 = bufA;            // M x 512 (reuses g0's region; g0 dead by then)
  k_gconv0<ST><<<2048, 256, 0, stream>>>(adj, x, wt0, cbs0, cbe0, g0);
  k_stats<ST><<<dim3(38, 32), 256, 0, stream>>>(g0, 256, stats);
  k_gconv1<ST><<<2048, 256, 0, stream>>>(adj, g0, wt1, cbs1, cbe1, stats, cg0, cb0, g1);
  k_stats<ST><<<dim3(38, 32), 256, 0, stream>>>(g1, 256, stats + 76);
  k_lin0<ST><<<2048, 256, 0, stream>>>(g1, wt2, lb0, stats + 76, cg1, cb1, g2);
  k_stats<ST><<<dim3(38, 32), 256, 0, stream>>>(g2, 512, stats + 152);
  k_final<ST><<<2048, 384, 0, stream>>>(g2, x, wt3, fb, stats + 152, lg0, lbb0, out);
}

extern "C" void kernel_launch(void* const* d_in, const int* in_sizes, int n_in,
                              void* d_out, int out_size, void* d_ws, size_t ws_size,
                              hipStream_t stream) {
  (void)in_sizes; (void)n_in; (void)out_size;
  const float* adj  = (const float*)d_in[0];
  const float* x    = (const float*)d_in[1];
  const float* cWs0 = (const float*)d_in[2];
  const float* cbs0 = (const float*)d_in[3];
  const float* cWe0 = (const float*)d_in[4];
  const float* cbe0 = (const float*)d_in[5];
  const float* cg0  = (const float*)d_in[6];
  const float* cb0  = (const float*)d_in[7];
  const float* cWs1 = (const float*)d_in[8];
  const float* cbs1 = (const float*)d_in[9];
  const float* cWe1 = (const float*)d_in[10];
  const float* cbe1 = (const float*)d_in[11];
  const float* cg1  = (const float*)d_in[12];
  const float* cb1  = (const float*)d_in[13];
  const float* lW0  = (const float*)d_in[14];
  const float* lb0  = (const float*)d_in[15];
  const float* lg0  = (const float*)d_in[16];
  const float* lbb0 = (const float*)d_in[17];
  const float* fW   = (const float*)d_in[18];
  const float* fb   = (const float*)d_in[19];
  float* out = (float*)d_out;

  float* ws = (float*)d_ws;
  float* stats = ws;                         // 256 floats
  float* wt0 = ws + 256;                     // 45*256
  float* wt1 = wt0 + 45 * 256;               // 1280*256
  float* wt2 = wt1 + 1280 * 256;             // 256*512
  float* wt3 = wt2 + 256 * 512;              // 512*18
  const size_t wfl = 256 + 45 * 256 + 1280 * 256 + 256 * 512 + 512 * 18;  // 479744 floats
  char* act = (char*)(ws + wfl);

  const size_t actElems = (size_t)M_ * 768;  // g2(M*512) + g1(M*256)
  const size_t need32 = wfl * 4 + actElems * 4;
  const bool use32 = ws_size >= need32;

  k_zero<<<1, 256, 0, stream>>>(stats);
  k_build_w0<<<45, 256, 0, stream>>>(cWs0, cWe0, wt0);
  k_build_w1<<<1280, 256, 0, stream>>>(cWs1, cWe1, wt1);
  k_build_w2<<<512, 256, 0, stream>>>(lW0, wt2);
  k_build_w3<<<36, 256, 0, stream>>>(fW, wt3);

  if (use32) {
    float* bufA = (float*)act;
    float* bufB = bufA + (size_t)M_ * 512;
    run_pipeline<float>(adj, x, cbs0, cbe0, cg0, cb0, cbs1, cbe1, cg1, cb1,
                        lb0, lg0, lbb0, fb, stats, wt0, wt1, wt2, wt3,
                        bufA, bufB, out, stream);
  } else {
    __hip_bfloat16* bufA = (__hip_bfloat16*)act;
    __hip_bfloat16* bufB = bufA + (size_t)M_ * 512;
    run_pipeline<__hip_bfloat16>(adj, x, cbs0, cbe0, cg0, cb0, cbs1, cbe1, cg1, cb1,
                                 lb0, lg0, lbb0, fb, stats, wt0, wt1, wt2, wt3,
                                 bufA, bufB, out, stream);
  }
}

// Round 3
// 720.086 us; speedup vs baseline: 2.4389x; 2.4389x over previous
//
#include <hip/hip_runtime.h>
#include <hip/hip_bf16.h>
#include <math.h>

#define B_   2048
#define N_   38
#define E_   4
#define DIN_ 9
#define H0_  256
#define H1_  256
#define L0_  512
#define M_   (B_ * N_)

typedef short bf16x8 __attribute__((ext_vector_type(8)));
typedef float f32x4 __attribute__((ext_vector_type(4)));

// ---------- bf16 helpers ----------
struct __align__(8) bf4 { __hip_bfloat16 x, y, z, w; };

__device__ __forceinline__ float b2f(unsigned short u) {
  return __uint_as_float((unsigned)u << 16);
}
__device__ __forceinline__ unsigned short f2b(float f) {
  __hip_bfloat16 h = __float2bfloat16(f);
  return *(unsigned short*)&h;
}

__device__ __forceinline__ float4 ld4v(const float* p) { return *(const float4*)p; }
__device__ __forceinline__ float4 ld4v(const __hip_bfloat16* p) {
  bf4 v = *(const bf4*)p;
  return make_float4(__bfloat162float(v.x), __bfloat162float(v.y),
                     __bfloat162float(v.z), __bfloat162float(v.w));
}
__device__ __forceinline__ void st4v(float* p, float4 v) { *(float4*)p = v; }
__device__ __forceinline__ void st4v(__hip_bfloat16* p, float4 v) {
  bf4 o;
  o.x = __float2bfloat16(v.x); o.y = __float2bfloat16(v.y);
  o.z = __float2bfloat16(v.z); o.w = __float2bfloat16(v.w);
  *(bf4*)p = o;
}
__device__ __forceinline__ float ld1v(const __hip_bfloat16* p) { return __bfloat162float(*p); }

static __device__ __forceinline__ float selc(const float4 v, int j) {
  return (j == 0) ? v.x : ((j == 1) ? v.y : ((j == 2) ? v.z : v.w));
}

__device__ __forceinline__ void fma_tile12(const float* __restrict__ zr, float4 w,
                                           float (&acc)[4][12]) {
#pragma unroll
  for (int l4 = 0; l4 < 3; ++l4) {
    float4 zv = *(const float4*)&zr[l4 * 4];
#pragma unroll
    for (int j = 0; j < 4; ++j) {
      float wj = selc(w, j);
      acc[j][l4 * 4 + 0] = fmaf(zv.x, wj, acc[j][l4 * 4 + 0]);
      acc[j][l4 * 4 + 1] = fmaf(zv.y, wj, acc[j][l4 * 4 + 1]);
      acc[j][l4 * 4 + 2] = fmaf(zv.z, wj, acc[j][l4 * 4 + 2]);
      acc[j][l4 * 4 + 3] = fmaf(zv.w, wj, acc[j][l4 * 4 + 3]);
    }
  }
}

__global__ void k_zero(float* __restrict__ p) { p[threadIdx.x] = 0.f; }

// wt0 fp32 [45][256]
__global__ void k_build_w0(const float* __restrict__ Ws, const float* __restrict__ We,
                           float* __restrict__ WT) {
  int i = blockIdx.x * 256 + threadIdx.x;
  if (i >= 45 * 256) return;
  int r = i / 256, c = i % 256;
  float v;
  if (r < 9) v = Ws[c * 9 + r];
  else { int rr = r - 9; int e = rr / 9, f = rr % 9; v = We[(c * 4 + e) * 9 + f]; }
  WT[i] = v;
}

// Wb1 bf16 [256][1280]: row c, col k: k<256 -> cWs1[c][k]; else e=(k-256)>>8,f=(k-256)&255 -> cWe1[c*4+e][f]
__global__ void k_build_wb1(const float* __restrict__ Ws, const float* __restrict__ We,
                            unsigned short* __restrict__ WT) {
  int i = blockIdx.x * 256 + threadIdx.x;
  if (i >= 256 * 1280) return;
  int c = i / 1280, k = i % 1280;
  float v;
  if (k < 256) v = Ws[c * 256 + k];
  else { int kk = k - 256; int e = kk >> 8, f = kk & 255; v = We[(c * 4 + e) * 256 + f]; }
  WT[i] = f2b(v);
}

// Wl bf16 [512][256] = cast of lW0
__global__ void k_build_wl(const float* __restrict__ W, unsigned short* __restrict__ WT) {
  int i = blockIdx.x * 256 + threadIdx.x;
  if (i >= 512 * 256) return;
  WT[i] = f2b(W[i]);
}

// fWT fp32 [512][18]
__global__ void k_build_w3(const float* __restrict__ W, float* __restrict__ WT) {
  int i = blockIdx.x * 256 + threadIdx.x;
  if (i >= 512 * 18) return;
  int k = i / 18, c = i % 18;
  WT[i] = W[c * 512 + k];
}

// ---------------- gconv layer 0 (K=45), fp32 VALU, output bf16 ----------------
__global__ __launch_bounds__(256) void k_gconv0(
    const float* __restrict__ adj, const float* __restrict__ x,
    const float* __restrict__ WT, const float* __restrict__ bs,
    const float* __restrict__ be, __hip_bfloat16* __restrict__ g) {
  __shared__ __align__(16) float adjF[E_ * N_ * N_];
  __shared__ __align__(16) float xc[45 * 48];
  __shared__ __align__(16) float arow[E_ * 48];
  const int b = blockIdx.x, tid = threadIdx.x;
  const size_t abase = (size_t)b * (E_ * N_ * N_);
  for (int i = tid; i < E_ * N_ * N_; i += 256) adjF[i] = adj[abase + i];
  for (int i = tid; i < N_ * DIN_; i += 256) {
    int n = i / DIN_;
    float v = x[(size_t)b * (N_ * DIN_) + i];
    xc[(i % DIN_) * 48 + n] = (n & 1) ? v : 0.f;   // MASK zeroes even rows
  }
  __syncthreads();
  for (int i = tid; i < E_ * N_; i += 256) {
    int e = i / N_, m = i % N_;
    const float* ar = &adjF[(e * N_ + m) * N_];
    float s = 0.f;
    for (int n = 0; n < N_; ++n) s += ar[n];
    arow[e * 48 + m] = s;
  }
  for (int i = tid; i < 36 * N_; i += 256) {
    int m = i % N_, ef = i / N_;
    int e = ef / 9, f = ef % 9;
    const float* ar = &adjF[(e * N_ + m) * N_];
    float s = 0.f;
    for (int n = 0; n < N_; ++n) s += ar[n] * xc[f * 48 + n];
    xc[(9 + ef) * 48 + m] = s;
  }
  __syncthreads();
  const int cg = tid & 63, mg = tid >> 6;
  const int c0 = cg * 4, mb = mg * 12;
  float acc[4][12];
#pragma unroll
  for (int j = 0; j < 4; ++j) {
    float bsv = bs[c0 + j];
    float b0 = be[(c0 + j) * 4 + 0], b1 = be[(c0 + j) * 4 + 1];
    float b2 = be[(c0 + j) * 4 + 2], b3 = be[(c0 + j) * 4 + 3];
#pragma unroll
    for (int l = 0; l < 12; ++l) {
      int m = mb + l;
      acc[j][l] = bsv + arow[0 * 48 + m] * b0 + arow[1 * 48 + m] * b1 +
                  arow[2 * 48 + m] * b2 + arow[3 * 48 + m] * b3;
    }
  }
  for (int k = 0; k < 45; ++k) {
    float4 w = *(const float4*)&WT[k * 256 + c0];
    fma_tile12(&xc[k * 48 + mb], w, acc);
  }
#pragma unroll
  for (int l = 0; l < 12; ++l) {
    int m = mb + l;
    if (m < N_) {
      float4 o; o.x = acc[0][l]; o.y = acc[1][l]; o.z = acc[2][l]; o.w = acc[3][l];
      st4v(&g[((size_t)b * N_ + m) * H0_ + c0], o);
    }
  }
}

// ---------------- BN stats (bf16 input): per-n sum/sumsq over (B x C); grid (38,32) ----------------
__global__ __launch_bounds__(256) void k_stats(const __hip_bfloat16* __restrict__ g, int C,
                                               float* __restrict__ st) {
  int n = blockIdx.x, s = blockIdx.y, tid = threadIdx.x;
  int C4 = C >> 2;
  float sum = 0.f, sq = 0.f;
  int per = 64 * C4;
  for (int j = tid; j < per; j += 256) {
    int bb = (s << 6) + j / C4, cc = j % C4;
    float4 v = ld4v(&g[((size_t)(bb * N_ + n) * C4 + cc) * 4]);
    sum += v.x + v.y + v.z + v.w;
    sq += v.x * v.x + v.y * v.y + v.z * v.z + v.w * v.w;
  }
  for (int off = 32; off; off >>= 1) {
    sum += __shfl_down(sum, off);
    sq += __shfl_down(sq, off);
  }
  __shared__ float rs[4], rq[4];
  int w = tid >> 6, l = tid & 63;
  if (!l) { rs[w] = sum; rq[w] = sq; }
  __syncthreads();
  if (!tid) {
    float S = 0.f, Q = 0.f;
    for (int i = 0; i < 4; ++i) { S += rs[i]; Q += rq[i]; }
    atomicAdd(&st[n * 2], S);
    atomicAdd(&st[n * 2 + 1], Q);
  }
}

// ---------------- prep1: BN0+ReLU (in-place bf16), z (fp32->bf16), arow ----------------
__global__ __launch_bounds__(256) void k_prep1(
    const float* __restrict__ adj, unsigned short* __restrict__ g0h1,
    unsigned short* __restrict__ Z, float* __restrict__ arowB,
    const float* __restrict__ st, const float* __restrict__ gam,
    const float* __restrict__ bet, int b_base) {
  __shared__ __align__(16) float hL[N_ * 260];       // [n][f] pad 260
  __shared__ __align__(16) float adjA[E_ * N_ * 40]; // [e][n][m] pad 40
  __shared__ float aS[N_], bS[N_];
  const int tid = threadIdx.x;
  const int b = b_base + blockIdx.x;
  if (tid < N_) {
    const float cnt = 2048.f * 256.f;
    float mu = st[tid * 2] / cnt;
    float var = st[tid * 2 + 1] / cnt - mu * mu;
    float a = rsqrtf(var + 1e-5f) * gam[tid];
    aS[tid] = a;
    bS[tid] = bet[tid] - mu * a;
  }
  __syncthreads();
  // BN+ReLU: g0 -> hL (fp32) and in-place bf16 rewrite
  for (int i = tid; i < N_ * 32; i += 256) {
    int n = i >> 5, c8 = (i & 31) * 8;
    size_t gi = ((size_t)b * N_ + n) * 256 + c8;
    uint4 u = *(const uint4*)&g0h1[gi];
    float a = aS[n], bb = bS[n];
    float v[8];
    v[0] = b2f((unsigned short)(u.x & 0xffff)); v[1] = b2f((unsigned short)(u.x >> 16));
    v[2] = b2f((unsigned short)(u.y & 0xffff)); v[3] = b2f((unsigned short)(u.y >> 16));
    v[4] = b2f((unsigned short)(u.z & 0xffff)); v[5] = b2f((unsigned short)(u.z >> 16));
    v[6] = b2f((unsigned short)(u.w & 0xffff)); v[7] = b2f((unsigned short)(u.w >> 16));
#pragma unroll
    for (int j = 0; j < 8; ++j) {
      v[j] = fmaxf(fmaf(v[j], a, bb), 0.f);
      hL[n * 260 + c8 + j] = v[j];
    }
    uint4 o;
    o.x = (unsigned)f2b(v[0]) | ((unsigned)f2b(v[1]) << 16);
    o.y = (unsigned)f2b(v[2]) | ((unsigned)f2b(v[3]) << 16);
    o.z = (unsigned)f2b(v[4]) | ((unsigned)f2b(v[5]) << 16);
    o.w = (unsigned)f2b(v[6]) | ((unsigned)f2b(v[7]) << 16);
    *(uint4*)&g0h1[gi] = o;
  }
  // stage adj -> [e][n][m]
  for (int i = tid; i < E_ * N_ * N_; i += 256) {
    int e = i / (N_ * N_), r = i % (N_ * N_), m = r / N_, n = r % N_;
    adjA[(e * N_ + n) * 40 + m] = adj[(size_t)b * (E_ * N_ * N_) + i];
  }
  __syncthreads();
  if (tid < E_ * N_) {
    int e = tid / N_, m = tid % N_;
    float s = 0.f;
    for (int n = 0; n < N_; ++n) s += adjA[(e * N_ + n) * 40 + m];
    arowB[((size_t)b * N_ + m) * 4 + e] = s;
  }
  // z: thread (e, f4): z[m][e*256+f4*4..+3] for all m
  const int e = tid >> 6, f4 = (tid & 63) * 4;
  const size_t zrow0 = (size_t)blockIdx.x * N_;
#pragma unroll
  for (int mt = 0; mt < 5; ++mt) {
    const int m0 = mt * 8;
    float4 za[8];
#pragma unroll
    for (int mi = 0; mi < 8; ++mi) za[mi] = make_float4(0.f, 0.f, 0.f, 0.f);
    for (int n = 0; n < N_; ++n) {
      float4 h4 = *(const float4*)&hL[n * 260 + f4];
      float4 aa = *(const float4*)&adjA[(e * N_ + n) * 40 + m0];
      float4 ab = *(const float4*)&adjA[(e * N_ + n) * 40 + m0 + 4];
      float av[8] = {aa.x, aa.y, aa.z, aa.w, ab.x, ab.y, ab.z, ab.w};
#pragma unroll
      for (int mi = 0; mi < 8; ++mi) {
        za[mi].x = fmaf(av[mi], h4.x, za[mi].x);
        za[mi].y = fmaf(av[mi], h4.y, za[mi].y);
        za[mi].z = fmaf(av[mi], h4.z, za[mi].z);
        za[mi].w = fmaf(av[mi], h4.w, za[mi].w);
      }
    }
#pragma unroll
    for (int mi = 0; mi < 8; ++mi) {
      int m = m0 + mi;
      if (m < N_) {
        uint2 o;
        o.x = (unsigned)f2b(za[mi].x) | ((unsigned)f2b(za[mi].y) << 16);
        o.y = (unsigned)f2b(za[mi].z) | ((unsigned)f2b(za[mi].w) << 16);
        *(uint2*)&Z[(zrow0 + m) * 1024 + e * 256 + f4] = o;
      }
    }
  }
}

// ---------------- MFMA GEMM: C[M][Cstride] = A[M][K] * Bw[N][K]^T + bias (+arow.be) ----------------
// MODE 1: A cols [0,256) from A0 (global rows, stride sA0), [256,K) from A1 (local rows, stride 1024),
//         epilogue adds arow.be term.  MODE 0: plain A0.
template <int MODE>
__global__ __launch_bounds__(256) void k_mm(
    const unsigned short* __restrict__ A0, const unsigned short* __restrict__ A1,
    const unsigned short* __restrict__ Bw, const float* __restrict__ bias,
    const float* __restrict__ be, const float* __restrict__ arw,
    unsigned short* __restrict__ Cout, int m_base, int kChunks, int sA0, int Cstride) {
  __shared__ __align__(16) unsigned short lA[64 * 32];
  __shared__ __align__(16) unsigned short lB[256 * 32];
  __shared__ float lbias[256];
  __shared__ float lbe[1024];
  const int t = threadIdx.x;
  const int tileM = blockIdx.x, n_base = blockIdx.y * 256;
  const int K = kChunks * 32;
  for (int i = t; i < 256; i += 256) lbias[i] = bias[n_base + i];
  if (MODE == 1)
    for (int i = t; i < 1024; i += 256) lbe[i] = be[i];

  const int w = t >> 6, L = t & 63;
  const int lrow = L & 15, quad = L >> 4;
  const int srow = t >> 2, sseg = (t & 3) * 8;

  f32x4 acc[4][4];
#pragma unroll
  for (int mt = 0; mt < 4; ++mt)
#pragma unroll
    for (int nt = 0; nt < 4; ++nt) acc[mt][nt] = (f32x4){0.f, 0.f, 0.f, 0.f};

  for (int ki = 0; ki < kChunks; ++ki) {
    // stage A (64 rows x 32 k, 16B per thread)
    {
      const unsigned short* gp;
      if (MODE == 1 && ki >= 8)
        gp = A1 + (size_t)(tileM * 64 + srow) * 1024 + (ki - 8) * 32 + sseg;
      else
        gp = A0 + (size_t)(m_base + tileM * 64 + srow) * sA0 + ki * 32 + sseg;
      __builtin_amdgcn_global_load_lds(
          (const __attribute__((address_space(1))) void*)gp,
          (__attribute__((address_space(3))) void*)(lA + w * 512), 16, 0, 0);
    }
    // stage B (256 rows x 32 k)
#pragma unroll
    for (int r = 0; r < 4; ++r) {
      const unsigned short* gp = Bw + (size_t)(n_base + r * 64 + srow) * K + ki * 32 + sseg;
      __builtin_amdgcn_global_load_lds(
          (const __attribute__((address_space(1))) void*)gp,
          (__attribute__((address_space(3))) void*)(lB + r * 2048 + w * 512), 16, 0, 0);
    }
    __syncthreads();
    bf16x8 af[4], bfr[4];
#pragma unroll
    for (int mt = 0; mt < 4; ++mt)
      af[mt] = *(const bf16x8*)&lA[(mt * 16 + lrow) * 32 + quad * 8];
#pragma unroll
    for (int nt = 0; nt < 4; ++nt)
      bfr[nt] = *(const bf16x8*)&lB[(w * 64 + nt * 16 + lrow) * 32 + quad * 8];
#pragma unroll
    for (int mt = 0; mt < 4; ++mt)
#pragma unroll
      for (int nt = 0; nt < 4; ++nt)
        acc[mt][nt] = __builtin_amdgcn_mfma_f32_16x16x32_bf16(af[mt], bfr[nt], acc[mt][nt], 0, 0, 0);
    __syncthreads();
  }
  // epilogue
#pragma unroll
  for (int mt = 0; mt < 4; ++mt) {
#pragma unroll
    for (int reg = 0; reg < 4; ++reg) {
      const int r_loc = tileM * 64 + mt * 16 + quad * 4 + reg;
      const size_t r_glob = (size_t)(m_base + r_loc);
      float4 ar;
      if (MODE == 1) ar = *(const float4*)&arw[r_glob * 4];
#pragma unroll
      for (int nt = 0; nt < 4; ++nt) {
        const int col = w * 64 + nt * 16 + lrow;
        float v = acc[mt][nt][reg] + lbias[col];
        if (MODE == 1) {
          float4 bev = *(const float4*)&lbe[col * 4];
          v += ar.x * bev.x + ar.y * bev.y + ar.z * bev.z + ar.w * bev.w;
        }
        Cout[r_glob * Cstride + n_base + col] = f2b(v);
      }
    }
  }
}

// ---------------- prep2: BN1+ReLU elementwise in-place (bf16) ----------------
__global__ __launch_bounds__(256) void k_prep2(
    unsigned short* __restrict__ g, const float* __restrict__ st,
    const float* __restrict__ gam, const float* __restrict__ bet) {
  size_t i = (size_t)blockIdx.x * 256 + threadIdx.x;  // 8-elem groups
  int n = (int)((i >> 5) % N_);
  const float cnt = 2048.f * 256.f;
  float mu = st[n * 2] / cnt;
  float var = st[n * 2 + 1] / cnt - mu * mu;
  float a = rsqrtf(var + 1e-5f) * gam[n];
  float bb = bet[n] - mu * a;
  uint4 u = *((const uint4*)g + i);
  uint4 o;
  unsigned* up = (unsigned*)&u;
  unsigned* op = (unsigned*)&o;
#pragma unroll
  for (int j = 0; j < 4; ++j) {
    float lo = b2f((unsigned short)(up[j] & 0xffff));
    float hi = b2f((unsigned short)(up[j] >> 16));
    lo = fmaxf(fmaf(lo, a, bb), 0.f);
    hi = fmaxf(fmaf(hi, a, bb), 0.f);
    op[j] = (unsigned)f2b(lo) | ((unsigned)f2b(hi) << 16);
  }
  *((uint4*)g + i) = o;
}

// ---------------- final linear 512->18 + coupling + logdet, BN2+ReLU fused ----------------
__global__ __launch_bounds__(384) void k_final(
    const __hip_bfloat16* __restrict__ g2, const float* __restrict__ x,
    const float* __restrict__ fWT, const float* __restrict__ fb,
    const float* __restrict__ st, const float* __restrict__ gam,
    const float* __restrict__ bet, float* __restrict__ out) {
  __shared__ __align__(16) float h3T[128 * 40];
  __shared__ float logits[N_ * 18];
  __shared__ float red[512];
  __shared__ float aS[N_], bS[N_];
  const int b = blockIdx.x, tid = threadIdx.x;
  if (tid < N_) {
    const float cnt = 2048.f * 512.f;
    float mu = st[tid * 2] / cnt;
    float var = st[tid * 2 + 1] / cnt - mu * mu;
    float a = rsqrtf(var + 1e-5f) * gam[tid];
    aS[tid] = a;
    bS[tid] = bet[tid] - mu * a;
  }
  __syncthreads();
  const bool act = tid < 342;
  const int m = tid / 9, cp = tid % 9, c0 = cp * 2;
  float acc0 = 0.f, acc1 = 0.f;
  if (act) { acc0 = fb[c0]; acc1 = fb[c0 + 1]; }
  for (int kc = 0; kc < 4; ++kc) {
    __syncthreads();
    for (int i = tid; i < N_ * 128; i += 384) {
      int mm = i >> 7, kl = i & 127;
      float raw = ld1v(&g2[((size_t)b * N_ + mm) * L0_ + (kc << 7) + kl]);
      h3T[kl * 40 + mm] = fmaxf(fmaf(raw, aS[mm], bS[mm]), 0.f);
    }
    __syncthreads();
    if (act) {
      for (int kl = 0; kl < 128; ++kl) {
        float v = h3T[kl * 40 + m];
        float2 w = *(const float2*)&fWT[((kc << 7) + kl) * 18 + c0];
        acc0 = fmaf(v, w.x, acc0);
        acc1 = fmaf(v, w.y, acc1);
      }
    }
  }
  __syncthreads();
  if (act) { logits[m * 18 + c0] = acc0; logits[m * 18 + c0 + 1] = acc1; }
  __syncthreads();
  float ls = 0.f;
  if (tid < 342) {
    int mm = tid / 9, d = tid % 9;
    float sl = logits[mm * 18 + d];
    float tv = logits[mm * 18 + 9 + d];
    float xv = x[((size_t)b * N_ + mm) * 9 + d];
    float sg = 1.f / (1.f + expf(-sl));
    float o = (mm & 1) ? xv : (xv + tv) * sg;
    out[((size_t)b * N_ + mm) * 9 + d] = o;
    ls = (sl >= 0.f) ? -log1pf(expf(-sl)) : (sl - log1pf(expf(sl)));
  }
  red[tid] = ls;
  for (int i = tid + 384; i < 512; i += 384) red[i] = 0.f;
  __syncthreads();
  for (int s = 256; s >= 1; s >>= 1) {
    if (tid < s) red[tid] += red[tid + s];
    __syncthreads();
  }
  if (!tid) out[(size_t)B_ * 342 + b] = red[0];
}

extern "C" void kernel_launch(void* const* d_in, const int* in_sizes, int n_in,
                              void* d_out, int out_size, void* d_ws, size_t ws_size,
                              hipStream_t stream) {
  (void)in_sizes; (void)n_in; (void)out_size;
  const float* adj  = (const float*)d_in[0];
  const float* x    = (const float*)d_in[1];
  const float* cWs0 = (const float*)d_in[2];
  const float* cbs0 = (const float*)d_in[3];
  const float* cWe0 = (const float*)d_in[4];
  const float* cbe0 = (const float*)d_in[5];
  const float* cg0  = (const float*)d_in[6];
  const float* cb0  = (const float*)d_in[7];
  const float* cWs1 = (const float*)d_in[8];
  const float* cbs1 = (const float*)d_in[9];
  const float* cWe1 = (const float*)d_in[10];
  const float* cbe1 = (const float*)d_in[11];
  const float* cg1  = (const float*)d_in[12];
  const float* cb1  = (const float*)d_in[13];
  const float* lW0  = (const float*)d_in[14];
  const float* lb0  = (const float*)d_in[15];
  const float* lg0  = (const float*)d_in[16];
  const float* lbb0 = (const float*)d_in[17];
  const float* fW   = (const float*)d_in[18];
  const float* fb   = (const float*)d_in[19];
  float* out = (float*)d_out;

  // ---- workspace layout (bytes) ----
  char* p = (char*)d_ws;
  float* stats = (float*)p;                     p += 1024;
  float* wt0   = (float*)p;                     p += 45 * 256 * 4;
  float* wt3   = (float*)p;                     p += 512 * 18 * 4;
  unsigned short* Wb1 = (unsigned short*)p;     p += 256 * 1280 * 2;
  unsigned short* Wl  = (unsigned short*)p;     p += 512 * 256 * 2;
  float* arowB = (float*)p;                     p += (size_t)M_ * 4 * 4;
  unsigned short* buf1 = (unsigned short*)p;    p += (size_t)M_ * 256 * 2;   // g0 / h1 (/ part of g2)
  unsigned short* bufZ = (unsigned short*)p;    // Z region, size depends on nsplit
  const size_t baseBytes = (size_t)((char*)bufZ - (char*)d_ws) + (size_t)M_ * 256 * 2; // + buf3
  // nsplit selection: Z bytes = (M_/nsplit)*1024*2
  int nsplit;
  if (ws_size >= baseBytes + (size_t)M_ * 1024 * 2)      nsplit = 1;
  else if (ws_size >= baseBytes + (size_t)M_ * 512 * 2)  nsplit = 2;
  else                                                    nsplit = 4;
  const size_t zBytes = ((size_t)M_ / nsplit) * 1024 * 2;
  unsigned short* buf3 = (unsigned short*)((char*)bufZ + zBytes);            // g1 / h2
  unsigned short* g2 = (nsplit == 4) ? buf1 : bufZ;  // nsplit==4: g2 spans buf1+bufZ (contiguous)

  k_zero<<<1, 256, 0, stream>>>(stats);
  k_build_w0<<<45, 256, 0, stream>>>(cWs0, cWe0, wt0);
  k_build_wb1<<<1280, 256, 0, stream>>>(cWs1, cWe1, Wb1);
  k_build_wl<<<512, 256, 0, stream>>>(lW0, Wl);
  k_build_w3<<<36, 256, 0, stream>>>(fW, wt3);

  // layer 0
  k_gconv0<<<2048, 256, 0, stream>>>(adj, x, wt0, cbs0, cbe0, (__hip_bfloat16*)buf1);
  k_stats<<<dim3(38, 32), 256, 0, stream>>>((const __hip_bfloat16*)buf1, 256, stats);

  // layer 1: prep (BN0+relu, z, arow) + MFMA GEMM, batch-split
  const int bPer = B_ / nsplit;
  for (int s = 0; s < nsplit; ++s) {
    k_prep1<<<bPer, 256, 0, stream>>>(adj, buf1, bufZ, arowB, stats, cg0, cb0, s * bPer);
    k_mm<1><<<dim3(bPer * N_ / 64, 1), 256, 0, stream>>>(
        buf1, bufZ, Wb1, cbs1, cbe1, arowB, buf3, s * bPer * N_, 40, 256, 256);
  }
  k_stats<<<dim3(38, 32), 256, 0, stream>>>((const __hip_bfloat16*)buf3, 256, stats + 76);

  // layer 2: BN1+relu in-place, then lin0 GEMM
  k_prep2<<<(M_ * 256 / 8 + 255) / 256, 256, 0, stream>>>(buf3, stats + 76, cg1, cb1);
  k_mm<0><<<dim3(M_ / 64, 2), 256, 0, stream>>>(
      buf3, (const unsigned short*)nullptr, Wl, lb0, (const float*)nullptr,
      (const float*)nullptr, g2, 0, 8, 256, 512);
  k_stats<<<dim3(38, 32), 256, 0, stream>>>((const __hip_bfloat16*)g2, 512, stats + 152);

  // final
  k_final<<<2048, 384, 0, stream>>>((const __hip_bfloat16*)g2, x, wt3, fb,
                                    stats + 152, lg0, lbb0, out);
}

// Round 4
// 551.465 us; speedup vs baseline: 3.1846x; 1.3058x over previous
//
#include <hip/hip_runtime.h>
#include <hip/hip_bf16.h>
#include <math.h>

#define B_   2048
#define N_   38
#define E_   4
#define DIN_ 9
#define H0_  256
#define H1_  256
#define L0_  512
#define M_   (B_ * N_)

typedef short bf16x8 __attribute__((ext_vector_type(8)));
typedef float f32x4 __attribute__((ext_vector_type(4)));

// ---------- bf16 helpers ----------
struct __align__(8) bf4 { __hip_bfloat16 x, y, z, w; };

__device__ __forceinline__ float b2f(unsigned short u) {
  return __uint_as_float((unsigned)u << 16);
}
__device__ __forceinline__ unsigned short f2b(float f) {
  __hip_bfloat16 h = __float2bfloat16(f);
  return *(unsigned short*)&h;
}

__device__ __forceinline__ float4 ld4v(const float* p) { return *(const float4*)p; }
__device__ __forceinline__ float4 ld4v(const __hip_bfloat16* p) {
  bf4 v = *(const bf4*)p;
  return make_float4(__bfloat162float(v.x), __bfloat162float(v.y),
                     __bfloat162float(v.z), __bfloat162float(v.w));
}
__device__ __forceinline__ void st4v(__hip_bfloat16* p, float4 v) {
  bf4 o;
  o.x = __float2bfloat16(v.x); o.y = __float2bfloat16(v.y);
  o.z = __float2bfloat16(v.z); o.w = __float2bfloat16(v.w);
  *(bf4*)p = o;
}

static __device__ __forceinline__ float selc(const float4 v, int j) {
  return (j == 0) ? v.x : ((j == 1) ? v.y : ((j == 2) ? v.z : v.w));
}

__device__ __forceinline__ void fma_tile12(const float* __restrict__ zr, float4 w,
                                           float (&acc)[4][12]) {
#pragma unroll
  for (int l4 = 0; l4 < 3; ++l4) {
    float4 zv = *(const float4*)&zr[l4 * 4];
#pragma unroll
    for (int j = 0; j < 4; ++j) {
      float wj = selc(w, j);
      acc[j][l4 * 4 + 0] = fmaf(zv.x, wj, acc[j][l4 * 4 + 0]);
      acc[j][l4 * 4 + 1] = fmaf(zv.y, wj, acc[j][l4 * 4 + 1]);
      acc[j][l4 * 4 + 2] = fmaf(zv.z, wj, acc[j][l4 * 4 + 2]);
      acc[j][l4 * 4 + 3] = fmaf(zv.w, wj, acc[j][l4 * 4 + 3]);
    }
  }
}

__global__ void k_zero(float* __restrict__ p) { p[threadIdx.x] = 0.f; }

// wt0 fp32 [45][256]
__global__ void k_build_w0(const float* __restrict__ Ws, const float* __restrict__ We,
                           float* __restrict__ WT) {
  int i = blockIdx.x * 256 + threadIdx.x;
  if (i >= 45 * 256) return;
  int r = i / 256, c = i % 256;
  float v;
  if (r < 9) v = Ws[c * 9 + r];
  else { int rr = r - 9; int e = rr / 9, f = rr % 9; v = We[(c * 4 + e) * 9 + f]; }
  WT[i] = v;
}

// Wb1 bf16 [256][1280]
__global__ void k_build_wb1(const float* __restrict__ Ws, const float* __restrict__ We,
                            unsigned short* __restrict__ WT) {
  int i = blockIdx.x * 256 + threadIdx.x;
  if (i >= 256 * 1280) return;
  int c = i / 1280, k = i % 1280;
  float v;
  if (k < 256) v = Ws[c * 256 + k];
  else { int kk = k - 256; int e = kk >> 8, f = kk & 255; v = We[(c * 4 + e) * 256 + f]; }
  WT[i] = f2b(v);
}

// Wl bf16 [512][256] = cast of lW0
__global__ void k_build_wl(const float* __restrict__ W, unsigned short* __restrict__ WT) {
  int i = blockIdx.x * 256 + threadIdx.x;
  if (i >= 512 * 256) return;
  WT[i] = f2b(W[i]);
}

// Wfb bf16 [32][512]: rows 0..17 = fW, rows 18..31 zero
__global__ void k_build_wf(const float* __restrict__ W, unsigned short* __restrict__ WT) {
  int i = blockIdx.x * 256 + threadIdx.x;
  if (i >= 32 * 512) return;
  int r = i / 512, k = i % 512;
  WT[i] = f2b(r < 18 ? W[r * 512 + k] : 0.f);
}

// ---------------- gconv layer 0 (K=45), fp32 VALU, output bf16 ----------------
__global__ __launch_bounds__(256) void k_gconv0(
    const float* __restrict__ adj, const float* __restrict__ x,
    const float* __restrict__ WT, const float* __restrict__ bs,
    const float* __restrict__ be, __hip_bfloat16* __restrict__ g) {
  __shared__ __align__(16) float adjF[E_ * N_ * N_];
  __shared__ __align__(16) float xc[45 * 48];
  __shared__ __align__(16) float arow[E_ * 48];
  const int b = blockIdx.x, tid = threadIdx.x;
  const size_t abase = (size_t)b * (E_ * N_ * N_);
  for (int i = tid; i < E_ * N_ * N_; i += 256) adjF[i] = adj[abase + i];
  for (int i = tid; i < N_ * DIN_; i += 256) {
    int n = i / DIN_;
    float v = x[(size_t)b * (N_ * DIN_) + i];
    xc[(i % DIN_) * 48 + n] = (n & 1) ? v : 0.f;   // MASK zeroes even rows
  }
  __syncthreads();
  for (int i = tid; i < E_ * N_; i += 256) {
    int e = i / N_, m = i % N_;
    const float* ar = &adjF[(e * N_ + m) * N_];
    float s = 0.f;
    for (int n = 0; n < N_; ++n) s += ar[n];
    arow[e * 48 + m] = s;
  }
  for (int i = tid; i < 36 * N_; i += 256) {
    int m = i % N_, ef = i / N_;
    int e = ef / 9, f = ef % 9;
    const float* ar = &adjF[(e * N_ + m) * N_];
    float s = 0.f;
    for (int n = 0; n < N_; ++n) s += ar[n] * xc[f * 48 + n];
    xc[(9 + ef) * 48 + m] = s;
  }
  __syncthreads();
  const int cg = tid & 63, mg = tid >> 6;
  const int c0 = cg * 4, mb = mg * 12;
  float acc[4][12];
#pragma unroll
  for (int j = 0; j < 4; ++j) {
    float bsv = bs[c0 + j];
    float b0 = be[(c0 + j) * 4 + 0], b1 = be[(c0 + j) * 4 + 1];
    float b2 = be[(c0 + j) * 4 + 2], b3 = be[(c0 + j) * 4 + 3];
#pragma unroll
    for (int l = 0; l < 12; ++l) {
      int m = mb + l;
      acc[j][l] = bsv + arow[0 * 48 + m] * b0 + arow[1 * 48 + m] * b1 +
                  arow[2 * 48 + m] * b2 + arow[3 * 48 + m] * b3;
    }
  }
  for (int k = 0; k < 45; ++k) {
    float4 w = *(const float4*)&WT[k * 256 + c0];
    fma_tile12(&xc[k * 48 + mb], w, acc);
  }
#pragma unroll
  for (int l = 0; l < 12; ++l) {
    int m = mb + l;
    if (m < N_) {
      float4 o; o.x = acc[0][l]; o.y = acc[1][l]; o.z = acc[2][l]; o.w = acc[3][l];
      st4v(&g[((size_t)b * N_ + m) * H0_ + c0], o);
    }
  }
}

// ---------------- BN stats (bf16 input): per-n sum/sumsq over (B x C); grid (38,32) ----------------
__global__ __launch_bounds__(256) void k_stats(const __hip_bfloat16* __restrict__ g, int C,
                                               float* __restrict__ st) {
  int n = blockIdx.x, s = blockIdx.y, tid = threadIdx.x;
  int C4 = C >> 2;
  float sum = 0.f, sq = 0.f;
  int per = 64 * C4;
  for (int j = tid; j < per; j += 256) {
    int bb = (s << 6) + j / C4, cc = j % C4;
    float4 v = ld4v(&g[((size_t)(bb * N_ + n) * C4 + cc) * 4]);
    sum += v.x + v.y + v.z + v.w;
    sq += v.x * v.x + v.y * v.y + v.z * v.z + v.w * v.w;
  }
  for (int off = 32; off; off >>= 1) {
    sum += __shfl_down(sum, off);
    sq += __shfl_down(sq, off);
  }
  __shared__ float rs[4], rq[4];
  int w = tid >> 6, l = tid & 63;
  if (!l) { rs[w] = sum; rq[w] = sq; }
  __syncthreads();
  if (!tid) {
    float S = 0.f, Q = 0.f;
    for (int i = 0; i < 4; ++i) { S += rs[i]; Q += rq[i]; }
    atomicAdd(&st[n * 2], S);
    atomicAdd(&st[n * 2 + 1], Q);
  }
}

// ---------------- prep1: BN0+ReLU (in-place bf16), z (fp32->bf16), arow ----------------
__global__ __launch_bounds__(256) void k_prep1(
    const float* __restrict__ adj, unsigned short* __restrict__ g0h1,
    unsigned short* __restrict__ Z, float* __restrict__ arowB,
    const float* __restrict__ st, const float* __restrict__ gam,
    const float* __restrict__ bet, int b_base) {
  __shared__ __align__(16) float hL[N_ * 260];       // [n][f] pad 260
  __shared__ __align__(16) float adjA[E_ * N_ * 40]; // [e][n][m] pad 40
  __shared__ float aS[N_], bS[N_];
  const int tid = threadIdx.x;
  const int b = b_base + blockIdx.x;
  if (tid < N_) {
    const float cnt = 2048.f * 256.f;
    float mu = st[tid * 2] / cnt;
    float var = st[tid * 2 + 1] / cnt - mu * mu;
    float a = rsqrtf(var + 1e-5f) * gam[tid];
    aS[tid] = a;
    bS[tid] = bet[tid] - mu * a;
  }
  __syncthreads();
  for (int i = tid; i < N_ * 32; i += 256) {
    int n = i >> 5, c8 = (i & 31) * 8;
    size_t gi = ((size_t)b * N_ + n) * 256 + c8;
    uint4 u = *(const uint4*)&g0h1[gi];
    float a = aS[n], bb = bS[n];
    float v[8];
    v[0] = b2f((unsigned short)(u.x & 0xffff)); v[1] = b2f((unsigned short)(u.x >> 16));
    v[2] = b2f((unsigned short)(u.y & 0xffff)); v[3] = b2f((unsigned short)(u.y >> 16));
    v[4] = b2f((unsigned short)(u.z & 0xffff)); v[5] = b2f((unsigned short)(u.z >> 16));
    v[6] = b2f((unsigned short)(u.w & 0xffff)); v[7] = b2f((unsigned short)(u.w >> 16));
#pragma unroll
    for (int j = 0; j < 8; ++j) {
      v[j] = fmaxf(fmaf(v[j], a, bb), 0.f);
      hL[n * 260 + c8 + j] = v[j];
    }
    uint4 o;
    o.x = (unsigned)f2b(v[0]) | ((unsigned)f2b(v[1]) << 16);
    o.y = (unsigned)f2b(v[2]) | ((unsigned)f2b(v[3]) << 16);
    o.z = (unsigned)f2b(v[4]) | ((unsigned)f2b(v[5]) << 16);
    o.w = (unsigned)f2b(v[6]) | ((unsigned)f2b(v[7]) << 16);
    *(uint4*)&g0h1[gi] = o;
  }
  for (int i = tid; i < E_ * N_ * N_; i += 256) {
    int e = i / (N_ * N_), r = i % (N_ * N_), m = r / N_, n = r % N_;
    adjA[(e * N_ + n) * 40 + m] = adj[(size_t)b * (E_ * N_ * N_) + i];
  }
  __syncthreads();
  if (tid < E_ * N_) {
    int e = tid / N_, m = tid % N_;
    float s = 0.f;
    for (int n = 0; n < N_; ++n) s += adjA[(e * N_ + n) * 40 + m];
    arowB[((size_t)b * N_ + m) * 4 + e] = s;
  }
  const int e = tid >> 6, f4 = (tid & 63) * 4;
  const size_t zrow0 = (size_t)blockIdx.x * N_;
#pragma unroll
  for (int mt = 0; mt < 5; ++mt) {
    const int m0 = mt * 8;
    float4 za[8];
#pragma unroll
    for (int mi = 0; mi < 8; ++mi) za[mi] = make_float4(0.f, 0.f, 0.f, 0.f);
    for (int n = 0; n < N_; ++n) {
      float4 h4 = *(const float4*)&hL[n * 260 + f4];
      float4 aa = *(const float4*)&adjA[(e * N_ + n) * 40 + m0];
      float4 ab = *(const float4*)&adjA[(e * N_ + n) * 40 + m0 + 4];
      float av[8] = {aa.x, aa.y, aa.z, aa.w, ab.x, ab.y, ab.z, ab.w};
#pragma unroll
      for (int mi = 0; mi < 8; ++mi) {
        za[mi].x = fmaf(av[mi], h4.x, za[mi].x);
        za[mi].y = fmaf(av[mi], h4.y, za[mi].y);
        za[mi].z = fmaf(av[mi], h4.z, za[mi].z);
        za[mi].w = fmaf(av[mi], h4.w, za[mi].w);
      }
    }
#pragma unroll
    for (int mi = 0; mi < 8; ++mi) {
      int m = m0 + mi;
      if (m < N_) {
        uint2 o;
        o.x = (unsigned)f2b(za[mi].x) | ((unsigned)f2b(za[mi].y) << 16);
        o.y = (unsigned)f2b(za[mi].z) | ((unsigned)f2b(za[mi].w) << 16);
        *(uint2*)&Z[(zrow0 + m) * 1024 + e * 256 + f4] = o;
      }
    }
  }
}

// ---------------- MFMA GEMM: C[M][Cstride] = A[M][K] * Bw[N][K]^T + bias (+arow.be) ----------------
template <int MODE>
__global__ __launch_bounds__(256) void k_mm(
    const unsigned short* __restrict__ A0, const unsigned short* __restrict__ A1,
    const unsigned short* __restrict__ Bw, const float* __restrict__ bias,
    const float* __restrict__ be, const float* __restrict__ arw,
    unsigned short* __restrict__ Cout, int m_base, int kChunks, int sA0, int Cstride) {
  __shared__ __align__(16) unsigned short lA[64 * 32];
  __shared__ __align__(16) unsigned short lB[256 * 32];
  __shared__ float lbias[256];
  __shared__ float lbe[1024];
  const int t = threadIdx.x;
  const int tileM = blockIdx.x, n_base = blockIdx.y * 256;
  const int K = kChunks * 32;
  for (int i = t; i < 256; i += 256) lbias[i] = bias[n_base + i];
  if (MODE == 1)
    for (int i = t; i < 1024; i += 256) lbe[i] = be[i];

  const int w = t >> 6, L = t & 63;
  const int lrow = L & 15, quad = L >> 4;
  const int srow = t >> 2, sseg = (t & 3) * 8;

  f32x4 acc[4][4];
#pragma unroll
  for (int mt = 0; mt < 4; ++mt)
#pragma unroll
    for (int nt = 0; nt < 4; ++nt) acc[mt][nt] = (f32x4){0.f, 0.f, 0.f, 0.f};

  for (int ki = 0; ki < kChunks; ++ki) {
    {
      const unsigned short* gp;
      if (MODE == 1 && ki >= 8)
        gp = A1 + (size_t)(tileM * 64 + srow) * 1024 + (ki - 8) * 32 + sseg;
      else
        gp = A0 + (size_t)(m_base + tileM * 64 + srow) * sA0 + ki * 32 + sseg;
      __builtin_amdgcn_global_load_lds(
          (const __attribute__((address_space(1))) void*)gp,
          (__attribute__((address_space(3))) void*)(lA + w * 512), 16, 0, 0);
    }
#pragma unroll
    for (int r = 0; r < 4; ++r) {
      const unsigned short* gp = Bw + (size_t)(n_base + r * 64 + srow) * K + ki * 32 + sseg;
      __builtin_amdgcn_global_load_lds(
          (const __attribute__((address_space(1))) void*)gp,
          (__attribute__((address_space(3))) void*)(lB + r * 2048 + w * 512), 16, 0, 0);
    }
    __syncthreads();
    bf16x8 af[4], bfr[4];
#pragma unroll
    for (int mt = 0; mt < 4; ++mt)
      af[mt] = *(const bf16x8*)&lA[(mt * 16 + lrow) * 32 + quad * 8];
#pragma unroll
    for (int nt = 0; nt < 4; ++nt)
      bfr[nt] = *(const bf16x8*)&lB[(w * 64 + nt * 16 + lrow) * 32 + quad * 8];
#pragma unroll
    for (int mt = 0; mt < 4; ++mt)
#pragma unroll
      for (int nt = 0; nt < 4; ++nt)
        acc[mt][nt] = __builtin_amdgcn_mfma_f32_16x16x32_bf16(af[mt], bfr[nt], acc[mt][nt], 0, 0, 0);
    __syncthreads();
  }
#pragma unroll
  for (int mt = 0; mt < 4; ++mt) {
#pragma unroll
    for (int reg = 0; reg < 4; ++reg) {
      const int r_loc = tileM * 64 + mt * 16 + quad * 4 + reg;
      const size_t r_glob = (size_t)(m_base + r_loc);
      float4 ar;
      if (MODE == 1) ar = *(const float4*)&arw[r_glob * 4];
#pragma unroll
      for (int nt = 0; nt < 4; ++nt) {
        const int col = w * 64 + nt * 16 + lrow;
        float v = acc[mt][nt][reg] + lbias[col];
        if (MODE == 1) {
          float4 bev = *(const float4*)&lbe[col * 4];
          v += ar.x * bev.x + ar.y * bev.y + ar.z * bev.z + ar.w * bev.w;
        }
        Cout[r_glob * Cstride + n_base + col] = f2b(v);
      }
    }
  }
}

// ---------------- prep2: BN1+ReLU elementwise in-place (bf16) ----------------
__global__ __launch_bounds__(256) void k_prep2(
    unsigned short* __restrict__ g, const float* __restrict__ st,
    const float* __restrict__ gam, const float* __restrict__ bet) {
  size_t i = (size_t)blockIdx.x * 256 + threadIdx.x;  // 8-elem groups
  int n = (int)((i >> 5) % N_);
  const float cnt = 2048.f * 256.f;
  float mu = st[n * 2] / cnt;
  float var = st[n * 2 + 1] / cnt - mu * mu;
  float a = rsqrtf(var + 1e-5f) * gam[n];
  float bb = bet[n] - mu * a;
  uint4 u = *((const uint4*)g + i);
  uint4 o;
  unsigned* up = (unsigned*)&u;
  unsigned* op = (unsigned*)&o;
#pragma unroll
  for (int j = 0; j < 4; ++j) {
    float lo = b2f((unsigned short)(up[j] & 0xffff));
    float hi = b2f((unsigned short)(up[j] >> 16));
    lo = fmaxf(fmaf(lo, a, bb), 0.f);
    hi = fmaxf(fmaf(hi, a, bb), 0.f);
    op[j] = (unsigned)f2b(lo) | ((unsigned)f2b(hi) << 16);
  }
  *((uint4*)g + i) = o;
}

// ---------------- final: MFMA 512->18 + coupling + logdet, BN2+ReLU fused ----------------
// One block per b, 256 threads (4 waves; waves 0..2 run MFMA m-tiles).
__global__ __launch_bounds__(256) void k_final(
    const unsigned short* __restrict__ g2, const float* __restrict__ x,
    const unsigned short* __restrict__ Wfb, const float* __restrict__ fb,
    const float* __restrict__ st, const float* __restrict__ gam,
    const float* __restrict__ bet, float* __restrict__ out) {
  __shared__ __align__(16) unsigned short hA[48 * 520];  // bf16, row-pad 520
  __shared__ float lgS[48 * 20];                         // logits [m][c<18], pad 20
  __shared__ float aS[N_], bS[N_], fbS[20], red[4];
  const int b = blockIdx.x, tid = threadIdx.x;
  if (tid < N_) {
    const float cnt = 2048.f * 512.f;
    float mu = st[tid * 2] / cnt;
    float var = st[tid * 2 + 1] / cnt - mu * mu;
    float a = rsqrtf(var + 1e-5f) * gam[tid];
    aS[tid] = a;
    bS[tid] = bet[tid] - mu * a;
  }
  if (tid >= 64 && tid < 82) fbS[tid - 64] = fb[tid - 64];
  __syncthreads();
  // stage g2 rows -> BN+ReLU -> bf16 LDS
  for (int i = tid; i < N_ * 64; i += 256) {
    int n = i >> 6, seg = (i & 63) * 8;
    uint4 u = *(const uint4*)&g2[((size_t)b * N_ + n) * 512 + seg];
    float a = aS[n], bb = bS[n];
    float v[8];
    v[0] = b2f((unsigned short)(u.x & 0xffff)); v[1] = b2f((unsigned short)(u.x >> 16));
    v[2] = b2f((unsigned short)(u.y & 0xffff)); v[3] = b2f((unsigned short)(u.y >> 16));
    v[4] = b2f((unsigned short)(u.z & 0xffff)); v[5] = b2f((unsigned short)(u.z >> 16));
    v[6] = b2f((unsigned short)(u.w & 0xffff)); v[7] = b2f((unsigned short)(u.w >> 16));
#pragma unroll
    for (int j = 0; j < 8; ++j) v[j] = fmaxf(fmaf(v[j], a, bb), 0.f);
    uint4 o;
    o.x = (unsigned)f2b(v[0]) | ((unsigned)f2b(v[1]) << 16);
    o.y = (unsigned)f2b(v[2]) | ((unsigned)f2b(v[3]) << 16);
    o.z = (unsigned)f2b(v[4]) | ((unsigned)f2b(v[5]) << 16);
    o.w = (unsigned)f2b(v[6]) | ((unsigned)f2b(v[7]) << 16);
    *(uint4*)&hA[n * 520 + seg] = o;
  }
  for (int i = tid; i < 10 * 64; i += 256) {  // zero rows 38..47
    int n = 38 + (i >> 6), seg = (i & 63) * 8;
    *(uint4*)&hA[n * 520 + seg] = make_uint4(0, 0, 0, 0);
  }
  __syncthreads();
  const int w = tid >> 6, L = tid & 63;
  const int lrow = L & 15, quad = L >> 4;
  if (w < 3) {
    f32x4 acc0 = (f32x4){0.f, 0.f, 0.f, 0.f}, acc1 = (f32x4){0.f, 0.f, 0.f, 0.f};
#pragma unroll
    for (int ki = 0; ki < 16; ++ki) {
      bf16x8 af = *(const bf16x8*)&hA[(w * 16 + lrow) * 520 + ki * 32 + quad * 8];
      bf16x8 b0 = *(const bf16x8*)&Wfb[(size_t)lrow * 512 + ki * 32 + quad * 8];
      bf16x8 b1 = *(const bf16x8*)&Wfb[(size_t)(16 + lrow) * 512 + ki * 32 + quad * 8];
      acc0 = __builtin_amdgcn_mfma_f32_16x16x32_bf16(af, b0, acc0, 0, 0, 0);
      acc1 = __builtin_amdgcn_mfma_f32_16x16x32_bf16(af, b1, acc1, 0, 0, 0);
    }
#pragma unroll
    for (int reg = 0; reg < 4; ++reg) {
      int m = w * 16 + quad * 4 + reg;
      if (m < N_) {
        lgS[m * 20 + lrow] = acc0[reg] + fbS[lrow];
        if (lrow < 2) lgS[m * 20 + 16 + lrow] = acc1[reg] + fbS[16 + lrow];
      }
    }
  }
  __syncthreads();
  float ls = 0.f;
  for (int ii = tid; ii < 342; ii += 256) {
    int mm = ii / 9, d = ii % 9;
    float sl = lgS[mm * 20 + d];
    float tv = lgS[mm * 20 + 9 + d];
    float xv = x[((size_t)b * N_ + mm) * 9 + d];
    float sg = 1.f / (1.f + expf(-sl));
    float o = (mm & 1) ? xv : (xv + tv) * sg;
    out[((size_t)b * N_ + mm) * 9 + d] = o;
    ls += (sl >= 0.f) ? -log1pf(expf(-sl)) : (sl - log1pf(expf(sl)));
  }
#pragma unroll
  for (int off = 32; off; off >>= 1) ls += __shfl_down(ls, off);
  if (L == 0) red[w] = ls;
  __syncthreads();
  if (tid == 0) out[(size_t)B_ * 342 + b] = red[0] + red[1] + red[2] + red[3];
}

extern "C" void kernel_launch(void* const* d_in, const int* in_sizes, int n_in,
                              void* d_out, int out_size, void* d_ws, size_t ws_size,
                              hipStream_t stream) {
  (void)in_sizes; (void)n_in; (void)out_size;
  const float* adj  = (const float*)d_in[0];
  const float* x    = (const float*)d_in[1];
  const float* cWs0 = (const float*)d_in[2];
  const float* cbs0 = (const float*)d_in[3];
  const float* cWe0 = (const float*)d_in[4];
  const float* cbe0 = (const float*)d_in[5];
  const float* cg0  = (const float*)d_in[6];
  const float* cb0  = (const float*)d_in[7];
  const float* cWs1 = (const float*)d_in[8];
  const float* cbs1 = (const float*)d_in[9];
  const float* cWe1 = (const float*)d_in[10];
  const float* cbe1 = (const float*)d_in[11];
  const float* cg1  = (const float*)d_in[12];
  const float* cb1  = (const float*)d_in[13];
  const float* lW0  = (const float*)d_in[14];
  const float* lb0  = (const float*)d_in[15];
  const float* lg0  = (const float*)d_in[16];
  const float* lbb0 = (const float*)d_in[17];
  const float* fW   = (const float*)d_in[18];
  const float* fb   = (const float*)d_in[19];
  float* out = (float*)d_out;

  // ---- workspace layout (bytes) ----
  char* p = (char*)d_ws;
  float* stats = (float*)p;                     p += 1024;
  float* wt0   = (float*)p;                     p += 45 * 256 * 4;
  unsigned short* Wfb = (unsigned short*)p;     p += 32 * 512 * 2;
  unsigned short* Wb1 = (unsigned short*)p;     p += 256 * 1280 * 2;
  unsigned short* Wl  = (unsigned short*)p;     p += 512 * 256 * 2;
  float* arowB = (float*)p;                     p += (size_t)M_ * 4 * 4;
  unsigned short* buf1 = (unsigned short*)p;    p += (size_t)M_ * 256 * 2;   // g0 / h1
  unsigned short* bufZ = (unsigned short*)p;    // Z region
  const size_t baseBytes = (size_t)((char*)bufZ - (char*)d_ws) + (size_t)M_ * 256 * 2;
  int nsplit;
  if (ws_size >= baseBytes + (size_t)M_ * 1024 * 2)      nsplit = 1;
  else if (ws_size >= baseBytes + (size_t)M_ * 512 * 2)  nsplit = 2;
  else                                                    nsplit = 4;
  const size_t zBytes = ((size_t)M_ / nsplit) * 1024 * 2;
  unsigned short* buf3 = (unsigned short*)((char*)bufZ + zBytes);            // g1 / h2
  unsigned short* g2 = (nsplit == 4) ? buf1 : bufZ;

  k_zero<<<1, 256, 0, stream>>>(stats);
  k_build_w0<<<45, 256, 0, stream>>>(cWs0, cWe0, wt0);
  k_build_wb1<<<1280, 256, 0, stream>>>(cWs1, cWe1, Wb1);
  k_build_wl<<<512, 256, 0, stream>>>(lW0, Wl);
  k_build_wf<<<64, 256, 0, stream>>>(fW, Wfb);

  // layer 0
  k_gconv0<<<2048, 256, 0, stream>>>(adj, x, wt0, cbs0, cbe0, (__hip_bfloat16*)buf1);
  k_stats<<<dim3(38, 32), 256, 0, stream>>>((const __hip_bfloat16*)buf1, 256, stats);

  // layer 1: prep + MFMA GEMM (batch-split)
  const int bPer = B_ / nsplit;
  for (int s = 0; s < nsplit; ++s) {
    k_prep1<<<bPer, 256, 0, stream>>>(adj, buf1, bufZ, arowB, stats, cg0, cb0, s * bPer);
    k_mm<1><<<dim3(bPer * N_ / 64, 1), 256, 0, stream>>>(
        buf1, bufZ, Wb1, cbs1, cbe1, arowB, buf3, s * bPer * N_, 40, 256, 256);
  }
  k_stats<<<dim3(38, 32), 256, 0, stream>>>((const __hip_bfloat16*)buf3, 256, stats + 76);

  // layer 2: BN1+relu in-place, then lin0 GEMM
  k_prep2<<<(M_ * 256 / 8 + 255) / 256, 256, 0, stream>>>(buf3, stats + 76, cg1, cb1);
  k_mm<0><<<dim3(M_ / 64, 2), 256, 0, stream>>>(
      buf3, (const unsigned short*)nullptr, Wl, lb0, (const float*)nullptr,
      (const float*)nullptr, g2, 0, 8, 256, 512);
  k_stats<<<dim3(38, 32), 256, 0, stream>>>((const __hip_bfloat16*)g2, 512, stats + 152);

  // final
  k_final<<<2048, 256, 0, stream>>>(g2, x, Wfb, fb, stats + 152, lg0, lbb0, out);
}